// Round 12
// baseline (112.708 us; speedup 1.0000x reference)
//
#include <hip/hip_runtime.h>
#include <math.h>

// PointConv round 12: LDS window-accumulator — cut TCC atomics ~30x.
//   k_zero_start: CSR offsets + agg zeroing + pos4 packing (r11 verbatim).
//   k_edges: r11 body, but MFMA2 partials accumulate into an LDS window
//     accumulator (row = window-rank via per-quarter scalar offset from the
//     window ballot); drain writes ONE coalesced 64-dword global op per
//     window-segment: atomic only for first/last segment (may be shared with
//     neighbor windows), plain store for interior segments (exclusive by
//     sortedness). Fallback to verbatim-r9 quarter-atomic path if ndw > 32.
//   k_out: r7/r9/r11 verbatim.
//   ws layout: start[n_out+1] + pos4[N_IN] (runtime-checked, r11 fallback).

typedef __attribute__((ext_vector_type(8))) short short8;
typedef __attribute__((ext_vector_type(4))) float f32x4;
typedef __attribute__((ext_vector_type(4))) int   int4v;
typedef __attribute__((ext_vector_type(2))) int   int2v;

union frag_u { int i[4]; short8 v; };

__device__ __forceinline__ float celu1(float x) {
    float m = fminf(x, 0.0f);
    return fmaxf(x, __expf(m) - 1.0f);
}
__device__ __forceinline__ int cvt_pk_bf16(float lo, float hi) {
    int r; asm("v_cvt_pk_bf16_f32 %0, %1, %2" : "=v"(r) : "v"(lo), "v"(hi)); return r;
}

// start[o]=lower_bound(out_index,o); zero agg; pack pos4[i]={pos_in[i], x_in[i]}
__global__ void k_zero_start(const int* __restrict__ oi, int* __restrict__ start,
                             f32x4* __restrict__ agg4, int n_out, int E, int nzero4,
                             const float* __restrict__ pos_in,
                             const float* __restrict__ x_in,
                             f32x4* __restrict__ pos4, int n_in) {
    const int t = blockIdx.x * blockDim.x + threadIdx.x;
    if (t <= E) {
        const int cur  = (t < E) ? oi[t] : n_out;
        const int prev = (t > 0) ? oi[t - 1] : -1;
        for (int o = prev + 1; o <= cur; ++o) start[o] = t;
    }
    if (pos4 != nullptr && t < n_in) {
        f32x4 v;
        v.x = pos_in[t*3+0]; v.y = pos_in[t*3+1]; v.z = pos_in[t*3+2];
        v.w = x_in[t];
        pos4[t] = v;
    }
    const f32x4 z = {0.f, 0.f, 0.f, 0.f};
    for (int i = t; i < nzero4; i += gridDim.x * blockDim.x) agg4[i] = z;
}

template<bool P4>
__global__ __launch_bounds__(256) void k_edges(
    const float* __restrict__ x_in, const float* __restrict__ pos_in,
    const f32x4* __restrict__ pos4,
    const float* __restrict__ pos_out, const int* __restrict__ in_index,
    const int* __restrict__ out_index,
    const float* __restrict__ W1, const float* __restrict__ W2,
    float* __restrict__ agg, int E, int nwin, int totwaves)
{
    __shared__ int   hbuf [4][64][10];   // padded rows (40B) -> conflict-light reads
    __shared__ float scoef[4][64];
    __shared__ int   srank[4][64];
    __shared__ int   snid [4][64];       // quarter-rank node ids (fallback path)
    __shared__ int   snidw[4][32];       // window-rank node ids (fast path)
    __shared__ float acc  [4][32][68];   // window accumulator, 68-pad -> 2-way banks

    const int wv = threadIdx.x >> 6, lane = threadIdx.x & 63;
    const int kcol = lane & 15, q = lane >> 4;

    // B1 = W2 fragments: B[kk=4q+i][n=j=jt*16+kcol], K upper half zero
    frag_u b1[4];
#pragma unroll
    for (int jt = 0; jt < 4; ++jt) {
        const int j = jt * 16 + kcol;
        b1[jt].i[0] = cvt_pk_bf16(W2[(4*q+0)*64 + j], W2[(4*q+1)*64 + j]);
        b1[jt].i[1] = cvt_pk_bf16(W2[(4*q+2)*64 + j], W2[(4*q+3)*64 + j]);
        b1[jt].i[2] = 0; b1[jt].i[3] = 0;
    }
    const f32x4 zero4 = {0.f, 0.f, 0.f, 0.f};

    for (int win = blockIdx.x * 4 + wv; win < nwin; win += totwaves) {
        const int e = win * 64 + lane;
        const bool valid = e < E;
        const int ec = valid ? e : E - 1;

        const int node = out_index[ec];
        const int idx  = in_index[ec];

        float xv, pix, piy, piz;
        if (P4) {
            const f32x4 pv = pos4[idx];          // ONE scattered 16B gather
            pix = pv.x; piy = pv.y; piz = pv.z; xv = pv.w;
        } else {
            xv  = x_in[idx];
            pix = pos_in[idx*3+0]; piy = pos_in[idx*3+1]; piz = pos_in[idx*3+2];
        }
        const float coef = valid ? xv : 0.0f;    // unnormalized; deg in k_out
        const float px = pix - pos_out[node*3+0];
        const float py = piy - pos_out[node*3+1];
        const float pz = piz - pos_out[node*3+2];

        // this lane's edge: all 16 h channels
        int hp[8];
#pragma unroll
        for (int c = 0; c < 8; ++c) {
            const float h0 = celu1(fmaf(pz, W1[32 + 2*c],     fmaf(py, W1[16 + 2*c],     px * W1[2*c])));
            const float h1 = celu1(fmaf(pz, W1[32 + 2*c + 1], fmaf(py, W1[16 + 2*c + 1], px * W1[2*c + 1])));
            hp[c] = cvt_pk_bf16(h0, h1);
        }
        *(int4v*)&hbuf[wv][lane][0] = *(const int4v*)&hp[0];
        *(int4v*)&hbuf[wv][lane][4] = *(const int4v*)&hp[4];

        // ---- segmentation ----
        // window-level heads (no forced quarter boundaries)
        const int prevn = __shfl_up(node, 1);
        const bool whead = (lane == 0) || (node != prevn);
        const unsigned long long wbal = __ballot(whead);
        const int ndw = __popcll(wbal);
        // quarter-level heads (forced at kcol==0) = window heads | quarter starts
        const unsigned long long qbal = wbal | 0x0001000100010001ULL;
        const unsigned mym = (unsigned)(qbal >> (q * 16)) & 0xFFFFu;
        const int rank = __popc(mym & ((2u << kcol) - 1)) - 1;

        scoef[wv][lane] = coef;
        srank[wv][lane] = rank;
        const bool qhead = (qbal >> lane) & 1ull;
        if (qhead) snid[wv][(lane & 48) + rank] = node;
        const int wrank = __popcll(wbal & ((2ULL << lane) - 1)) - 1;
        if (whead && wrank < 32) snidw[wv][wrank] = node;

        int ndq[4];
#pragma unroll
        for (int Q = 0; Q < 4; ++Q) ndq[Q] = __popc((unsigned)(qbal >> (Q * 16)) & 0xFFFFu);

        if (ndw <= 32) {
            // ======== fast path: LDS window accumulator ========
            for (int s = 0; s < ndw; ++s) acc[wv][s][lane] = 0.0f;

#pragma unroll
            for (int Q = 0; Q < 4; ++Q) {
                const int2v a1lo = *(const int2v*)&hbuf[wv][Q*16 + kcol][2*q];
                frag_u a1; a1.i[0] = a1lo.x; a1.i[1] = a1lo.y; a1.i[2] = 0; a1.i[3] = 0;

                const f32x4 c4 = *(const f32x4*)&scoef[wv][Q*16 + 4*q];
                const int4v r4 = *(const int4v*)&srank[wv][Q*16 + 4*q];

                frag_u a2;
                a2.i[0] = cvt_pk_bf16(r4.x == kcol ? c4.x : 0.0f, r4.y == kcol ? c4.y : 0.0f);
                a2.i[1] = cvt_pk_bf16(r4.z == kcol ? c4.z : 0.0f, r4.w == kcol ? c4.w : 0.0f);
                a2.i[2] = 0; a2.i[3] = 0;

                const int nd = ndq[Q];
                // window-rank of this quarter's first lane (scalar)
                const int rowQ = __popcll(wbal & ((1ULL << (Q*16 + 1)) - 1)) - 1;

#pragma unroll
                for (int jt = 0; jt < 4; ++jt) {
                    f32x4 d1 = __builtin_amdgcn_mfma_f32_16x16x32_bf16(a1.v, b1[jt].v, zero4, 0, 0, 0);
                    frag_u b2;
                    b2.i[0] = cvt_pk_bf16(celu1(d1[0]), celu1(d1[1]));
                    b2.i[1] = cvt_pk_bf16(celu1(d1[2]), celu1(d1[3]));
                    b2.i[2] = 0; b2.i[3] = 0;
                    f32x4 d2 = __builtin_amdgcn_mfma_f32_16x16x32_bf16(a2.v, b2.v, zero4, 0, 0, 0);
                    const int colj = jt * 16 + kcol;
                    if (4*q + 0 < nd) atomicAdd(&acc[wv][rowQ + 4*q + 0][colj], d2[0]);
                    if (4*q + 1 < nd) atomicAdd(&acc[wv][rowQ + 4*q + 1][colj], d2[1]);
                    if (4*q + 2 < nd) atomicAdd(&acc[wv][rowQ + 4*q + 2][colj], d2[2]);
                    if (4*q + 3 < nd) atomicAdd(&acc[wv][rowQ + 4*q + 3][colj], d2[3]);
                }
            }

            // drain: one coalesced 64-dword global op per window-segment
            for (int s = 0; s < ndw; ++s) {
                const int ns = snidw[wv][s];
                const float v = acc[wv][s][lane];
                float* p = agg + (long)ns * 64 + lane;
                if (s == 0 || s == ndw - 1) unsafeAtomicAdd(p, v);  // may be shared with neighbor window
                else *p = v;                                        // interior: exclusive
            }
        } else {
            // ======== fallback: verbatim r9 quarter-atomic path ========
#pragma unroll
            for (int Q = 0; Q < 4; ++Q) {
                const int2v a1lo = *(const int2v*)&hbuf[wv][Q*16 + kcol][2*q];
                frag_u a1; a1.i[0] = a1lo.x; a1.i[1] = a1lo.y; a1.i[2] = 0; a1.i[3] = 0;

                const f32x4 c4 = *(const f32x4*)&scoef[wv][Q*16 + 4*q];
                const int4v r4 = *(const int4v*)&srank[wv][Q*16 + 4*q];
                const int4v n4 = *(const int4v*)&snid [wv][Q*16 + 4*q];

                frag_u a2;
                a2.i[0] = cvt_pk_bf16(r4.x == kcol ? c4.x : 0.0f, r4.y == kcol ? c4.y : 0.0f);
                a2.i[1] = cvt_pk_bf16(r4.z == kcol ? c4.z : 0.0f, r4.w == kcol ? c4.w : 0.0f);
                a2.i[2] = 0; a2.i[3] = 0;

                const int nd = ndq[Q];
                float* p0 = agg + (long)n4.x * 64 + kcol;
                float* p1 = agg + (long)n4.y * 64 + kcol;
                float* p2 = agg + (long)n4.z * 64 + kcol;
                float* p3 = agg + (long)n4.w * 64 + kcol;

#pragma unroll
                for (int jt = 0; jt < 4; ++jt) {
                    f32x4 d1 = __builtin_amdgcn_mfma_f32_16x16x32_bf16(a1.v, b1[jt].v, zero4, 0, 0, 0);
                    frag_u b2;
                    b2.i[0] = cvt_pk_bf16(celu1(d1[0]), celu1(d1[1]));
                    b2.i[1] = cvt_pk_bf16(celu1(d1[2]), celu1(d1[3]));
                    b2.i[2] = 0; b2.i[3] = 0;
                    f32x4 d2 = __builtin_amdgcn_mfma_f32_16x16x32_bf16(a2.v, b2.v, zero4, 0, 0, 0);
                    if (4*q + 0 < nd) unsafeAtomicAdd(p0 + jt * 16, d2[0]);
                    if (4*q + 1 < nd) unsafeAtomicAdd(p1 + jt * 16, d2[1]);
                    if (4*q + 2 < nd) unsafeAtomicAdd(p2 + jt * 16, d2[2]);
                    if (4*q + 3 < nd) unsafeAtomicAdd(p3 + jt * 16, d2[3]);
                }
            }
        }
    }
}

__global__ __launch_bounds__(256) void k_out(
    float* __restrict__ agg, const float* __restrict__ W3,
    const float* __restrict__ b3, const int* __restrict__ start,
    int n_out, int ntiles, int totwaves)
{
    const int wv = threadIdx.x >> 6, lane = threadIdx.x & 63;
    const int s = lane & 15, q = lane >> 4;

    frag_u B0[4], B1[4];
    float bias[4];
#pragma unroll
    for (int jt = 0; jt < 4; ++jt) {
        const int j = jt * 16 + s;
        bias[jt] = b3[j];
        B0[jt].i[0] = cvt_pk_bf16(W3[( 4*q+0)*64+j], W3[( 4*q+1)*64+j]);
        B0[jt].i[1] = cvt_pk_bf16(W3[( 4*q+2)*64+j], W3[( 4*q+3)*64+j]);
        B0[jt].i[2] = cvt_pk_bf16(W3[(16+4*q+0)*64+j], W3[(16+4*q+1)*64+j]);
        B0[jt].i[3] = cvt_pk_bf16(W3[(16+4*q+2)*64+j], W3[(16+4*q+3)*64+j]);
        B1[jt].i[0] = cvt_pk_bf16(W3[(32+4*q+0)*64+j], W3[(32+4*q+1)*64+j]);
        B1[jt].i[1] = cvt_pk_bf16(W3[(32+4*q+2)*64+j], W3[(32+4*q+3)*64+j]);
        B1[jt].i[2] = cvt_pk_bf16(W3[(48+4*q+0)*64+j], W3[(48+4*q+1)*64+j]);
        B1[jt].i[3] = cvt_pk_bf16(W3[(48+4*q+2)*64+j], W3[(48+4*q+3)*64+j]);
    }
    const f32x4 zero4 = {0.f, 0.f, 0.f, 0.f};

    for (int tile = blockIdx.x * 4 + wv; tile < ntiles; tile += totwaves) {
        const long base = (long)tile * 16;

        const long row_i = base + s;
        const long row_c = row_i < n_out ? row_i : n_out - 1;
        const float* row = agg + row_c * 64;
        const int dd = start[row_c + 1] - start[row_c];
        const float invd = 1.0f / (float)(dd > 0 ? dd : 1);

        f32x4 r0 = *(const f32x4*)(row +      4*q);
        f32x4 r1 = *(const f32x4*)(row + 16 + 4*q);
        f32x4 r2 = *(const f32x4*)(row + 32 + 4*q);
        f32x4 r3 = *(const f32x4*)(row + 48 + 4*q);
        r0 *= invd; r1 *= invd; r2 *= invd; r3 *= invd;

        frag_u A0, A1;
        A0.i[0] = cvt_pk_bf16(r0.x, r0.y); A0.i[1] = cvt_pk_bf16(r0.z, r0.w);
        A0.i[2] = cvt_pk_bf16(r1.x, r1.y); A0.i[3] = cvt_pk_bf16(r1.z, r1.w);
        A1.i[0] = cvt_pk_bf16(r2.x, r2.y); A1.i[1] = cvt_pk_bf16(r2.z, r2.w);
        A1.i[2] = cvt_pk_bf16(r3.x, r3.y); A1.i[3] = cvt_pk_bf16(r3.z, r3.w);

#pragma unroll
        for (int jt = 0; jt < 4; ++jt) {
            f32x4 d = __builtin_amdgcn_mfma_f32_16x16x32_bf16(A0.v, B0[jt].v, zero4, 0, 0, 0);
            d = __builtin_amdgcn_mfma_f32_16x16x32_bf16(A1.v, B1[jt].v, d, 0, 0, 0);
            const int j = jt * 16 + s;
#pragma unroll
            for (int r = 0; r < 4; ++r) {
                const long nodei = base + 4*q + r;
                if (nodei < n_out) {
                    float v = d[r] + bias[jt];
                    if (isnan(v)) v = 0.0f;
                    else if (isinf(v)) v = (v > 0.0f) ? 1e6f : -1e6f;
                    agg[nodei * 64 + j] = v;
                }
            }
        }
    }
}

extern "C" void kernel_launch(void* const* d_in, const int* in_sizes, int n_in_args,
                              void* d_out, int out_size, void* d_ws, size_t ws_size,
                              hipStream_t stream) {
    const float* x_in      = (const float*)d_in[0];
    const float* pos_in    = (const float*)d_in[1];
    // d_in[2] = batch_in (unused)
    const float* pos_out   = (const float*)d_in[3];
    const int*   in_index  = (const int*)d_in[4];
    const int*   out_index = (const int*)d_in[5];
    const float* W1        = (const float*)d_in[6];
    const float* W2        = (const float*)d_in[7];
    const float* W3        = (const float*)d_in[8];
    const float* b3        = (const float*)d_in[9];
    float* out = (float*)d_out;

    const int n_out = in_sizes[3] / 3;   // pos_out is [N_OUT, 3]
    const int E     = in_sizes[4];
    const int n_in  = in_sizes[0];       // x_in is [N_IN, 1]

    // ws layout: start[n_out+1] | pos4[n_in] (16B aligned)
    int* start = (int*)d_ws;
    const size_t start_bytes = ((size_t)(n_out + 1) * 4 + 255) & ~(size_t)255;
    const size_t need = start_bytes + (size_t)n_in * 16;
    const bool use_p4 = (ws_size >= need);
    f32x4* pos4 = use_p4 ? (f32x4*)((char*)d_ws + start_bytes) : nullptr;

    {
        const int nzero4 = n_out * 16;                  // n_out*64 floats / 4
        int span = (E + 1) > nzero4 ? (E + 1) : nzero4;
        if (n_in > span) span = n_in;
        dim3 b(256), g((span + 255) / 256);
        k_zero_start<<<g, b, 0, stream>>>(out_index, start, (f32x4*)out, n_out, E,
                                          nzero4, pos_in, x_in, pos4, n_in);
    }

    {
        const int nwin = (E + 63) / 64;              // 64 edges per window
        const int nblocks = (nwin + 7) / 8;          // 4 waves x 2 windows/wave
        const int totwaves = nblocks * 4;
        if (use_p4)
            k_edges<true><<<dim3(nblocks), dim3(256), 0, stream>>>(
                x_in, pos_in, pos4, pos_out, in_index, out_index, W1, W2, out, E, nwin, totwaves);
        else
            k_edges<false><<<dim3(nblocks), dim3(256), 0, stream>>>(
                x_in, pos_in, pos4, pos_out, in_index, out_index, W1, W2, out, E, nwin, totwaves);
    }
    {
        const int ntiles = (n_out + 15) / 16;        // 16 nodes per tile
        const int nblocks = (ntiles + 7) / 8;        // ~2 tiles per wave
        const int totwaves = nblocks * 4;
        k_out<<<dim3(nblocks), dim3(256), 0, stream>>>(
            out, W3, b3, start, n_out, ntiles, totwaves);
    }
}

// Round 13
// 74.330 us; speedup vs baseline: 1.5163x; 1.5163x over previous
//
#include <hip/hip_runtime.h>
#include <math.h>

// PointConv round 13: register D2 accumulation across quarters (window-rank MFMA2).
//   Base = r11 (best verified: 77.3us). Only k_edges' inner loop changes:
//   - segmentation at WINDOW level (ndw segments, ndw<=16 for ~all windows)
//   - A2 rows = window ranks; D2 accumulates across the 4 quarters via the
//     MFMA C operand (registers, no LDS accumulator, no occupancy cost)
//   - ONE atomic phase per window: 16 guarded atomics instead of 64
//   - ndw>16 windows: verbatim r9 quarter-atomic fallback (wave-uniform branch)
//   k_zero_start / k_out / launcher: r11 verbatim.

typedef __attribute__((ext_vector_type(8))) short short8;
typedef __attribute__((ext_vector_type(4))) float f32x4;
typedef __attribute__((ext_vector_type(4))) int   int4v;
typedef __attribute__((ext_vector_type(2))) int   int2v;

union frag_u { int i[4]; short8 v; };

__device__ __forceinline__ float celu1(float x) {
    float m = fminf(x, 0.0f);
    return fmaxf(x, __expf(m) - 1.0f);
}
__device__ __forceinline__ int cvt_pk_bf16(float lo, float hi) {
    int r; asm("v_cvt_pk_bf16_f32 %0, %1, %2" : "=v"(r) : "v"(lo), "v"(hi)); return r;
}

// start[o]=lower_bound(out_index,o); zero agg; pack pos4[i]={pos_in[i], x_in[i]}
__global__ void k_zero_start(const int* __restrict__ oi, int* __restrict__ start,
                             f32x4* __restrict__ agg4, int n_out, int E, int nzero4,
                             const float* __restrict__ pos_in,
                             const float* __restrict__ x_in,
                             f32x4* __restrict__ pos4, int n_in) {
    const int t = blockIdx.x * blockDim.x + threadIdx.x;
    if (t <= E) {
        const int cur  = (t < E) ? oi[t] : n_out;
        const int prev = (t > 0) ? oi[t - 1] : -1;
        for (int o = prev + 1; o <= cur; ++o) start[o] = t;
    }
    if (pos4 != nullptr && t < n_in) {
        f32x4 v;
        v.x = pos_in[t*3+0]; v.y = pos_in[t*3+1]; v.z = pos_in[t*3+2];
        v.w = x_in[t];
        pos4[t] = v;
    }
    const f32x4 z = {0.f, 0.f, 0.f, 0.f};
    for (int i = t; i < nzero4; i += gridDim.x * blockDim.x) agg4[i] = z;
}

template<bool P4>
__global__ __launch_bounds__(256) void k_edges(
    const float* __restrict__ x_in, const float* __restrict__ pos_in,
    const f32x4* __restrict__ pos4,
    const float* __restrict__ pos_out, const int* __restrict__ in_index,
    const int* __restrict__ out_index,
    const float* __restrict__ W1, const float* __restrict__ W2,
    float* __restrict__ agg, int E, int nwin, int totwaves)
{
    __shared__ int   hbuf [4][64][10];   // padded rows (40B) -> conflict-light reads
    __shared__ float scoef[4][64];
    __shared__ int   srank[4][64];       // window-rank (fast) or quarter-rank (fallback)
    __shared__ int   snid [4][64];       // quarter-rank node ids (fallback path)
    __shared__ int   snidw[4][16];       // window-rank node ids (fast path)

    const int wv = threadIdx.x >> 6, lane = threadIdx.x & 63;
    const int kcol = lane & 15, q = lane >> 4;

    // B1 = W2 fragments: B[kk=4q+i][n=j=jt*16+kcol], K upper half zero
    frag_u b1[4];
#pragma unroll
    for (int jt = 0; jt < 4; ++jt) {
        const int j = jt * 16 + kcol;
        b1[jt].i[0] = cvt_pk_bf16(W2[(4*q+0)*64 + j], W2[(4*q+1)*64 + j]);
        b1[jt].i[1] = cvt_pk_bf16(W2[(4*q+2)*64 + j], W2[(4*q+3)*64 + j]);
        b1[jt].i[2] = 0; b1[jt].i[3] = 0;
    }
    const f32x4 zero4 = {0.f, 0.f, 0.f, 0.f};

    for (int win = blockIdx.x * 4 + wv; win < nwin; win += totwaves) {
        const int e = win * 64 + lane;
        const bool valid = e < E;
        const int ec = valid ? e : E - 1;

        const int node = out_index[ec];
        const int idx  = in_index[ec];

        float xv, pix, piy, piz;
        if (P4) {
            const f32x4 pv = pos4[idx];          // ONE scattered 16B gather
            pix = pv.x; piy = pv.y; piz = pv.z; xv = pv.w;
        } else {
            xv  = x_in[idx];
            pix = pos_in[idx*3+0]; piy = pos_in[idx*3+1]; piz = pos_in[idx*3+2];
        }
        const float coef = valid ? xv : 0.0f;    // unnormalized; deg in k_out
        const float px = pix - pos_out[node*3+0];
        const float py = piy - pos_out[node*3+1];
        const float pz = piz - pos_out[node*3+2];

        // this lane's edge: all 16 h channels
        int hp[8];
#pragma unroll
        for (int c = 0; c < 8; ++c) {
            const float h0 = celu1(fmaf(pz, W1[32 + 2*c],     fmaf(py, W1[16 + 2*c],     px * W1[2*c])));
            const float h1 = celu1(fmaf(pz, W1[32 + 2*c + 1], fmaf(py, W1[16 + 2*c + 1], px * W1[2*c + 1])));
            hp[c] = cvt_pk_bf16(h0, h1);
        }
        *(int4v*)&hbuf[wv][lane][0] = *(const int4v*)&hp[0];
        *(int4v*)&hbuf[wv][lane][4] = *(const int4v*)&hp[4];

        // ---- window-level segmentation ----
        const int prevn = __shfl_up(node, 1);
        const bool whead = (lane == 0) || (node != prevn);
        const unsigned long long wbal = __ballot(whead);
        const int ndw = __popcll(wbal);

        scoef[wv][lane] = coef;

        if (ndw <= 16) {
            // ======== fast path: window-rank MFMA2, D2 accumulated in registers ========
            const int wrank = __popcll(wbal & ((2ULL << lane) - 1)) - 1;
            srank[wv][lane] = wrank;
            if (whead) snidw[wv][wrank] = node;

            f32x4 d2acc[4] = {zero4, zero4, zero4, zero4};

#pragma unroll
            for (int Q = 0; Q < 4; ++Q) {
                // A1[m=slot=kcol][kk=4q+i] = h of edge Q*16+kcol (LDS transpose read)
                const int2v a1lo = *(const int2v*)&hbuf[wv][Q*16 + kcol][2*q];
                frag_u a1; a1.i[0] = a1lo.x; a1.i[1] = a1lo.y; a1.i[2] = 0; a1.i[3] = 0;

                const f32x4 c4 = *(const f32x4*)&scoef[wv][Q*16 + 4*q];
                const int4v r4 = *(const int4v*)&srank[wv][Q*16 + 4*q];

                // A2[m=window-rank=kcol][kk=slot 4q+i] = coef if wrank[kk]==m else 0
                frag_u a2;
                a2.i[0] = cvt_pk_bf16(r4.x == kcol ? c4.x : 0.0f, r4.y == kcol ? c4.y : 0.0f);
                a2.i[1] = cvt_pk_bf16(r4.z == kcol ? c4.z : 0.0f, r4.w == kcol ? c4.w : 0.0f);
                a2.i[2] = 0; a2.i[3] = 0;

#pragma unroll
                for (int jt = 0; jt < 4; ++jt) {
                    f32x4 d1 = __builtin_amdgcn_mfma_f32_16x16x32_bf16(a1.v, b1[jt].v, zero4, 0, 0, 0);
                    frag_u b2;
                    b2.i[0] = cvt_pk_bf16(celu1(d1[0]), celu1(d1[1]));
                    b2.i[1] = cvt_pk_bf16(celu1(d1[2]), celu1(d1[3]));
                    b2.i[2] = 0; b2.i[3] = 0;
                    // accumulate this quarter into the window accumulator (C operand)
                    d2acc[jt] = __builtin_amdgcn_mfma_f32_16x16x32_bf16(a2.v, b2.v, d2acc[jt], 0, 0, 0);
                }
            }

            // ONE atomic phase per window: rows = window segments
            const int4v n4 = *(const int4v*)&snidw[wv][4*q & 15];   // 4q..4q+3 (q<4 -> safe)
            float* p0 = agg + (long)n4.x * 64 + kcol;
            float* p1 = agg + (long)n4.y * 64 + kcol;
            float* p2 = agg + (long)n4.z * 64 + kcol;
            float* p3 = agg + (long)n4.w * 64 + kcol;
#pragma unroll
            for (int jt = 0; jt < 4; ++jt) {
                if (4*q + 0 < ndw) unsafeAtomicAdd(p0 + jt * 16, d2acc[jt][0]);
                if (4*q + 1 < ndw) unsafeAtomicAdd(p1 + jt * 16, d2acc[jt][1]);
                if (4*q + 2 < ndw) unsafeAtomicAdd(p2 + jt * 16, d2acc[jt][2]);
                if (4*q + 3 < ndw) unsafeAtomicAdd(p3 + jt * 16, d2acc[jt][3]);
            }
        } else {
            // ======== fallback: verbatim r9 quarter-atomic path ========
            const unsigned long long qbal = wbal | 0x0001000100010001ULL;
            const unsigned mym = (unsigned)(qbal >> (q * 16)) & 0xFFFFu;
            const int rank = __popc(mym & ((2u << kcol) - 1)) - 1;
            srank[wv][lane] = rank;
            const bool qhead = (qbal >> lane) & 1ull;
            if (qhead) snid[wv][(lane & 48) + rank] = node;

            int ndq[4];
#pragma unroll
            for (int Q = 0; Q < 4; ++Q) ndq[Q] = __popc((unsigned)(qbal >> (Q * 16)) & 0xFFFFu);

#pragma unroll
            for (int Q = 0; Q < 4; ++Q) {
                const int2v a1lo = *(const int2v*)&hbuf[wv][Q*16 + kcol][2*q];
                frag_u a1; a1.i[0] = a1lo.x; a1.i[1] = a1lo.y; a1.i[2] = 0; a1.i[3] = 0;

                const f32x4 c4 = *(const f32x4*)&scoef[wv][Q*16 + 4*q];
                const int4v r4 = *(const int4v*)&srank[wv][Q*16 + 4*q];
                const int4v n4 = *(const int4v*)&snid [wv][Q*16 + 4*q];

                frag_u a2;
                a2.i[0] = cvt_pk_bf16(r4.x == kcol ? c4.x : 0.0f, r4.y == kcol ? c4.y : 0.0f);
                a2.i[1] = cvt_pk_bf16(r4.z == kcol ? c4.z : 0.0f, r4.w == kcol ? c4.w : 0.0f);
                a2.i[2] = 0; a2.i[3] = 0;

                const int nd = ndq[Q];
                float* p0 = agg + (long)n4.x * 64 + kcol;
                float* p1 = agg + (long)n4.y * 64 + kcol;
                float* p2 = agg + (long)n4.z * 64 + kcol;
                float* p3 = agg + (long)n4.w * 64 + kcol;

#pragma unroll
                for (int jt = 0; jt < 4; ++jt) {
                    f32x4 d1 = __builtin_amdgcn_mfma_f32_16x16x32_bf16(a1.v, b1[jt].v, zero4, 0, 0, 0);
                    frag_u b2;
                    b2.i[0] = cvt_pk_bf16(celu1(d1[0]), celu1(d1[1]));
                    b2.i[1] = cvt_pk_bf16(celu1(d1[2]), celu1(d1[3]));
                    b2.i[2] = 0; b2.i[3] = 0;
                    f32x4 d2 = __builtin_amdgcn_mfma_f32_16x16x32_bf16(a2.v, b2.v, zero4, 0, 0, 0);
                    if (4*q + 0 < nd) unsafeAtomicAdd(p0 + jt * 16, d2[0]);
                    if (4*q + 1 < nd) unsafeAtomicAdd(p1 + jt * 16, d2[1]);
                    if (4*q + 2 < nd) unsafeAtomicAdd(p2 + jt * 16, d2[2]);
                    if (4*q + 3 < nd) unsafeAtomicAdd(p3 + jt * 16, d2[3]);
                }
            }
        }
    }
}

__global__ __launch_bounds__(256) void k_out(
    float* __restrict__ agg, const float* __restrict__ W3,
    const float* __restrict__ b3, const int* __restrict__ start,
    int n_out, int ntiles, int totwaves)
{
    const int wv = threadIdx.x >> 6, lane = threadIdx.x & 63;
    const int s = lane & 15, q = lane >> 4;

    frag_u B0[4], B1[4];
    float bias[4];
#pragma unroll
    for (int jt = 0; jt < 4; ++jt) {
        const int j = jt * 16 + s;
        bias[jt] = b3[j];
        B0[jt].i[0] = cvt_pk_bf16(W3[( 4*q+0)*64+j], W3[( 4*q+1)*64+j]);
        B0[jt].i[1] = cvt_pk_bf16(W3[( 4*q+2)*64+j], W3[( 4*q+3)*64+j]);
        B0[jt].i[2] = cvt_pk_bf16(W3[(16+4*q+0)*64+j], W3[(16+4*q+1)*64+j]);
        B0[jt].i[3] = cvt_pk_bf16(W3[(16+4*q+2)*64+j], W3[(16+4*q+3)*64+j]);
        B1[jt].i[0] = cvt_pk_bf16(W3[(32+4*q+0)*64+j], W3[(32+4*q+1)*64+j]);
        B1[jt].i[1] = cvt_pk_bf16(W3[(32+4*q+2)*64+j], W3[(32+4*q+3)*64+j]);
        B1[jt].i[2] = cvt_pk_bf16(W3[(48+4*q+0)*64+j], W3[(48+4*q+1)*64+j]);
        B1[jt].i[3] = cvt_pk_bf16(W3[(48+4*q+2)*64+j], W3[(48+4*q+3)*64+j]);
    }
    const f32x4 zero4 = {0.f, 0.f, 0.f, 0.f};

    for (int tile = blockIdx.x * 4 + wv; tile < ntiles; tile += totwaves) {
        const long base = (long)tile * 16;

        const long row_i = base + s;
        const long row_c = row_i < n_out ? row_i : n_out - 1;
        const float* row = agg + row_c * 64;
        const int dd = start[row_c + 1] - start[row_c];
        const float invd = 1.0f / (float)(dd > 0 ? dd : 1);

        f32x4 r0 = *(const f32x4*)(row +      4*q);
        f32x4 r1 = *(const f32x4*)(row + 16 + 4*q);
        f32x4 r2 = *(const f32x4*)(row + 32 + 4*q);
        f32x4 r3 = *(const f32x4*)(row + 48 + 4*q);
        r0 *= invd; r1 *= invd; r2 *= invd; r3 *= invd;

        frag_u A0, A1;
        A0.i[0] = cvt_pk_bf16(r0.x, r0.y); A0.i[1] = cvt_pk_bf16(r0.z, r0.w);
        A0.i[2] = cvt_pk_bf16(r1.x, r1.y); A0.i[3] = cvt_pk_bf16(r1.z, r1.w);
        A1.i[0] = cvt_pk_bf16(r2.x, r2.y); A1.i[1] = cvt_pk_bf16(r2.z, r2.w);
        A1.i[2] = cvt_pk_bf16(r3.x, r3.y); A1.i[3] = cvt_pk_bf16(r3.z, r3.w);

#pragma unroll
        for (int jt = 0; jt < 4; ++jt) {
            f32x4 d = __builtin_amdgcn_mfma_f32_16x16x32_bf16(A0.v, B0[jt].v, zero4, 0, 0, 0);
            d = __builtin_amdgcn_mfma_f32_16x16x32_bf16(A1.v, B1[jt].v, d, 0, 0, 0);
            const int j = jt * 16 + s;
#pragma unroll
            for (int r = 0; r < 4; ++r) {
                const long nodei = base + 4*q + r;
                if (nodei < n_out) {
                    float v = d[r] + bias[jt];
                    if (isnan(v)) v = 0.0f;
                    else if (isinf(v)) v = (v > 0.0f) ? 1e6f : -1e6f;
                    agg[nodei * 64 + j] = v;
                }
            }
        }
    }
}

extern "C" void kernel_launch(void* const* d_in, const int* in_sizes, int n_in_args,
                              void* d_out, int out_size, void* d_ws, size_t ws_size,
                              hipStream_t stream) {
    const float* x_in      = (const float*)d_in[0];
    const float* pos_in    = (const float*)d_in[1];
    // d_in[2] = batch_in (unused)
    const float* pos_out   = (const float*)d_in[3];
    const int*   in_index  = (const int*)d_in[4];
    const int*   out_index = (const int*)d_in[5];
    const float* W1        = (const float*)d_in[6];
    const float* W2        = (const float*)d_in[7];
    const float* W3        = (const float*)d_in[8];
    const float* b3        = (const float*)d_in[9];
    float* out = (float*)d_out;

    const int n_out = in_sizes[3] / 3;   // pos_out is [N_OUT, 3]
    const int E     = in_sizes[4];
    const int n_in  = in_sizes[0];       // x_in is [N_IN, 1]

    // ws layout: start[n_out+1] | pos4[n_in] (16B aligned)
    int* start = (int*)d_ws;
    const size_t start_bytes = ((size_t)(n_out + 1) * 4 + 255) & ~(size_t)255;
    const size_t need = start_bytes + (size_t)n_in * 16;
    const bool use_p4 = (ws_size >= need);
    f32x4* pos4 = use_p4 ? (f32x4*)((char*)d_ws + start_bytes) : nullptr;

    {
        const int nzero4 = n_out * 16;                  // n_out*64 floats / 4
        int span = (E + 1) > nzero4 ? (E + 1) : nzero4;
        if (n_in > span) span = n_in;
        dim3 b(256), g((span + 255) / 256);
        k_zero_start<<<g, b, 0, stream>>>(out_index, start, (f32x4*)out, n_out, E,
                                          nzero4, pos_in, x_in, pos4, n_in);
    }

    {
        const int nwin = (E + 63) / 64;              // 64 edges per window
        const int nblocks = (nwin + 7) / 8;          // 4 waves x 2 windows/wave
        const int totwaves = nblocks * 4;
        if (use_p4)
            k_edges<true><<<dim3(nblocks), dim3(256), 0, stream>>>(
                x_in, pos_in, pos4, pos_out, in_index, out_index, W1, W2, out, E, nwin, totwaves);
        else
            k_edges<false><<<dim3(nblocks), dim3(256), 0, stream>>>(
                x_in, pos_in, pos4, pos_out, in_index, out_index, W1, W2, out, E, nwin, totwaves);
    }
    {
        const int ntiles = (n_out + 15) / 16;        // 16 nodes per tile
        const int nblocks = (ntiles + 7) / 8;        // ~2 tiles per wave
        const int totwaves = nblocks * 4;
        k_out<<<dim3(nblocks), dim3(256), 0, stream>>>(
            out, W3, b3, start, n_out, ntiles, totwaves);
    }
}

// Round 14
// 70.914 us; speedup vs baseline: 1.5894x; 1.0482x over previous
//
#include <hip/hip_runtime.h>
#include <math.h>

// PointConv round 14: r13 body + 1-window-per-wave grid + pos_out4 packing.
//   k_zero_start: CSR offsets + agg zeroing + pos4/pos_out4 packing (tiered).
//   k_edges<TIER>: r13 verbatim inner logic. TIER2: pos4 + pos_out4 gathers;
//     TIER1: pos4 only; TIER0: raw loads. Window-rank MFMA2 with register D2
//     accumulation (16 atomics/window), r9 quarter-atomic fallback for ndw>16.
//   k_out: verbatim.
//   Grid: 1 window per wave (6250 blocks) -> wave churn overlaps atomic drain
//   of finishing waves with gather latency of fresh waves.

typedef __attribute__((ext_vector_type(8))) short short8;
typedef __attribute__((ext_vector_type(4))) float f32x4;
typedef __attribute__((ext_vector_type(4))) int   int4v;
typedef __attribute__((ext_vector_type(2))) int   int2v;

union frag_u { int i[4]; short8 v; };

__device__ __forceinline__ float celu1(float x) {
    float m = fminf(x, 0.0f);
    return fmaxf(x, __expf(m) - 1.0f);
}
__device__ __forceinline__ int cvt_pk_bf16(float lo, float hi) {
    int r; asm("v_cvt_pk_bf16_f32 %0, %1, %2" : "=v"(r) : "v"(lo), "v"(hi)); return r;
}

// start[o]=lower_bound(out_index,o); zero agg; pack pos4[i]={pos_in[i],x_in[i]},
// pos_out4[o]={pos_out[o],0}
__global__ void k_zero_start(const int* __restrict__ oi, int* __restrict__ start,
                             f32x4* __restrict__ agg4, int n_out, int E, int nzero4,
                             const float* __restrict__ pos_in,
                             const float* __restrict__ x_in,
                             f32x4* __restrict__ pos4, int n_in,
                             const float* __restrict__ pos_out,
                             f32x4* __restrict__ pos_out4) {
    const int t = blockIdx.x * blockDim.x + threadIdx.x;
    if (t <= E) {
        const int cur  = (t < E) ? oi[t] : n_out;
        const int prev = (t > 0) ? oi[t - 1] : -1;
        for (int o = prev + 1; o <= cur; ++o) start[o] = t;
    }
    if (pos4 != nullptr && t < n_in) {
        f32x4 v;
        v.x = pos_in[t*3+0]; v.y = pos_in[t*3+1]; v.z = pos_in[t*3+2];
        v.w = x_in[t];
        pos4[t] = v;
    }
    if (pos_out4 != nullptr && t < n_out) {
        f32x4 v;
        v.x = pos_out[t*3+0]; v.y = pos_out[t*3+1]; v.z = pos_out[t*3+2];
        v.w = 0.0f;
        pos_out4[t] = v;
    }
    const f32x4 z = {0.f, 0.f, 0.f, 0.f};
    for (int i = t; i < nzero4; i += gridDim.x * blockDim.x) agg4[i] = z;
}

template<int TIER>
__global__ __launch_bounds__(256) void k_edges(
    const float* __restrict__ x_in, const float* __restrict__ pos_in,
    const f32x4* __restrict__ pos4, const f32x4* __restrict__ pos_out4,
    const float* __restrict__ pos_out, const int* __restrict__ in_index,
    const int* __restrict__ out_index,
    const float* __restrict__ W1, const float* __restrict__ W2,
    float* __restrict__ agg, int E, int nwin, int totwaves)
{
    __shared__ int   hbuf [4][64][10];   // padded rows (40B) -> conflict-light reads
    __shared__ float scoef[4][64];
    __shared__ int   srank[4][64];       // window-rank (fast) or quarter-rank (fallback)
    __shared__ int   snid [4][64];       // quarter-rank node ids (fallback path)
    __shared__ int   snidw[4][16];       // window-rank node ids (fast path)

    const int wv = threadIdx.x >> 6, lane = threadIdx.x & 63;
    const int kcol = lane & 15, q = lane >> 4;

    // B1 = W2 fragments: B[kk=4q+i][n=j=jt*16+kcol], K upper half zero
    frag_u b1[4];
#pragma unroll
    for (int jt = 0; jt < 4; ++jt) {
        const int j = jt * 16 + kcol;
        b1[jt].i[0] = cvt_pk_bf16(W2[(4*q+0)*64 + j], W2[(4*q+1)*64 + j]);
        b1[jt].i[1] = cvt_pk_bf16(W2[(4*q+2)*64 + j], W2[(4*q+3)*64 + j]);
        b1[jt].i[2] = 0; b1[jt].i[3] = 0;
    }
    const f32x4 zero4 = {0.f, 0.f, 0.f, 0.f};

    for (int win = blockIdx.x * 4 + wv; win < nwin; win += totwaves) {
        const int e = win * 64 + lane;
        const bool valid = e < E;
        const int ec = valid ? e : E - 1;

        const int node = out_index[ec];
        const int idx  = in_index[ec];

        float xv, pix, piy, piz;
        if (TIER >= 1) {
            const f32x4 pv = pos4[idx];          // ONE scattered 16B gather
            pix = pv.x; piy = pv.y; piz = pv.z; xv = pv.w;
        } else {
            xv  = x_in[idx];
            pix = pos_in[idx*3+0]; piy = pos_in[idx*3+1]; piz = pos_in[idx*3+2];
        }
        float pox, poy, poz;
        if (TIER >= 2) {
            const f32x4 po = pos_out4[node];     // ONE 16B (mostly-broadcast) load
            pox = po.x; poy = po.y; poz = po.z;
        } else {
            pox = pos_out[node*3+0]; poy = pos_out[node*3+1]; poz = pos_out[node*3+2];
        }
        const float coef = valid ? xv : 0.0f;    // unnormalized; deg in k_out
        const float px = pix - pox;
        const float py = piy - poy;
        const float pz = piz - poz;

        // this lane's edge: all 16 h channels
        int hp[8];
#pragma unroll
        for (int c = 0; c < 8; ++c) {
            const float h0 = celu1(fmaf(pz, W1[32 + 2*c],     fmaf(py, W1[16 + 2*c],     px * W1[2*c])));
            const float h1 = celu1(fmaf(pz, W1[32 + 2*c + 1], fmaf(py, W1[16 + 2*c + 1], px * W1[2*c + 1])));
            hp[c] = cvt_pk_bf16(h0, h1);
        }
        *(int4v*)&hbuf[wv][lane][0] = *(const int4v*)&hp[0];
        *(int4v*)&hbuf[wv][lane][4] = *(const int4v*)&hp[4];

        // ---- window-level segmentation ----
        const int prevn = __shfl_up(node, 1);
        const bool whead = (lane == 0) || (node != prevn);
        const unsigned long long wbal = __ballot(whead);
        const int ndw = __popcll(wbal);

        scoef[wv][lane] = coef;

        if (ndw <= 16) {
            // ======== fast path: window-rank MFMA2, D2 accumulated in registers ========
            const int wrank = __popcll(wbal & ((2ULL << lane) - 1)) - 1;
            srank[wv][lane] = wrank;
            if (whead) snidw[wv][wrank] = node;

            f32x4 d2acc[4] = {zero4, zero4, zero4, zero4};

#pragma unroll
            for (int Q = 0; Q < 4; ++Q) {
                const int2v a1lo = *(const int2v*)&hbuf[wv][Q*16 + kcol][2*q];
                frag_u a1; a1.i[0] = a1lo.x; a1.i[1] = a1lo.y; a1.i[2] = 0; a1.i[3] = 0;

                const f32x4 c4 = *(const f32x4*)&scoef[wv][Q*16 + 4*q];
                const int4v r4 = *(const int4v*)&srank[wv][Q*16 + 4*q];

                frag_u a2;
                a2.i[0] = cvt_pk_bf16(r4.x == kcol ? c4.x : 0.0f, r4.y == kcol ? c4.y : 0.0f);
                a2.i[1] = cvt_pk_bf16(r4.z == kcol ? c4.z : 0.0f, r4.w == kcol ? c4.w : 0.0f);
                a2.i[2] = 0; a2.i[3] = 0;

#pragma unroll
                for (int jt = 0; jt < 4; ++jt) {
                    f32x4 d1 = __builtin_amdgcn_mfma_f32_16x16x32_bf16(a1.v, b1[jt].v, zero4, 0, 0, 0);
                    frag_u b2;
                    b2.i[0] = cvt_pk_bf16(celu1(d1[0]), celu1(d1[1]));
                    b2.i[1] = cvt_pk_bf16(celu1(d1[2]), celu1(d1[3]));
                    b2.i[2] = 0; b2.i[3] = 0;
                    d2acc[jt] = __builtin_amdgcn_mfma_f32_16x16x32_bf16(a2.v, b2.v, d2acc[jt], 0, 0, 0);
                }
            }

            // ONE atomic phase per window
            const int4v n4 = *(const int4v*)&snidw[wv][4*q & 15];
            float* p0 = agg + (long)n4.x * 64 + kcol;
            float* p1 = agg + (long)n4.y * 64 + kcol;
            float* p2 = agg + (long)n4.z * 64 + kcol;
            float* p3 = agg + (long)n4.w * 64 + kcol;
#pragma unroll
            for (int jt = 0; jt < 4; ++jt) {
                if (4*q + 0 < ndw) unsafeAtomicAdd(p0 + jt * 16, d2acc[jt][0]);
                if (4*q + 1 < ndw) unsafeAtomicAdd(p1 + jt * 16, d2acc[jt][1]);
                if (4*q + 2 < ndw) unsafeAtomicAdd(p2 + jt * 16, d2acc[jt][2]);
                if (4*q + 3 < ndw) unsafeAtomicAdd(p3 + jt * 16, d2acc[jt][3]);
            }
        } else {
            // ======== fallback: verbatim r9 quarter-atomic path ========
            const unsigned long long qbal = wbal | 0x0001000100010001ULL;
            const unsigned mym = (unsigned)(qbal >> (q * 16)) & 0xFFFFu;
            const int rank = __popc(mym & ((2u << kcol) - 1)) - 1;
            srank[wv][lane] = rank;
            const bool qhead = (qbal >> lane) & 1ull;
            if (qhead) snid[wv][(lane & 48) + rank] = node;

            int ndq[4];
#pragma unroll
            for (int Q = 0; Q < 4; ++Q) ndq[Q] = __popc((unsigned)(qbal >> (Q * 16)) & 0xFFFFu);

#pragma unroll
            for (int Q = 0; Q < 4; ++Q) {
                const int2v a1lo = *(const int2v*)&hbuf[wv][Q*16 + kcol][2*q];
                frag_u a1; a1.i[0] = a1lo.x; a1.i[1] = a1lo.y; a1.i[2] = 0; a1.i[3] = 0;

                const f32x4 c4 = *(const f32x4*)&scoef[wv][Q*16 + 4*q];
                const int4v r4 = *(const int4v*)&srank[wv][Q*16 + 4*q];
                const int4v n4 = *(const int4v*)&snid [wv][Q*16 + 4*q];

                frag_u a2;
                a2.i[0] = cvt_pk_bf16(r4.x == kcol ? c4.x : 0.0f, r4.y == kcol ? c4.y : 0.0f);
                a2.i[1] = cvt_pk_bf16(r4.z == kcol ? c4.z : 0.0f, r4.w == kcol ? c4.w : 0.0f);
                a2.i[2] = 0; a2.i[3] = 0;

                const int nd = ndq[Q];
                float* p0 = agg + (long)n4.x * 64 + kcol;
                float* p1 = agg + (long)n4.y * 64 + kcol;
                float* p2 = agg + (long)n4.z * 64 + kcol;
                float* p3 = agg + (long)n4.w * 64 + kcol;

#pragma unroll
                for (int jt = 0; jt < 4; ++jt) {
                    f32x4 d1 = __builtin_amdgcn_mfma_f32_16x16x32_bf16(a1.v, b1[jt].v, zero4, 0, 0, 0);
                    frag_u b2;
                    b2.i[0] = cvt_pk_bf16(celu1(d1[0]), celu1(d1[1]));
                    b2.i[1] = cvt_pk_bf16(celu1(d1[2]), celu1(d1[3]));
                    b2.i[2] = 0; b2.i[3] = 0;
                    f32x4 d2 = __builtin_amdgcn_mfma_f32_16x16x32_bf16(a2.v, b2.v, zero4, 0, 0, 0);
                    if (4*q + 0 < nd) unsafeAtomicAdd(p0 + jt * 16, d2[0]);
                    if (4*q + 1 < nd) unsafeAtomicAdd(p1 + jt * 16, d2[1]);
                    if (4*q + 2 < nd) unsafeAtomicAdd(p2 + jt * 16, d2[2]);
                    if (4*q + 3 < nd) unsafeAtomicAdd(p3 + jt * 16, d2[3]);
                }
            }
        }
    }
}

__global__ __launch_bounds__(256) void k_out(
    float* __restrict__ agg, const float* __restrict__ W3,
    const float* __restrict__ b3, const int* __restrict__ start,
    int n_out, int ntiles, int totwaves)
{
    const int wv = threadIdx.x >> 6, lane = threadIdx.x & 63;
    const int s = lane & 15, q = lane >> 4;

    frag_u B0[4], B1[4];
    float bias[4];
#pragma unroll
    for (int jt = 0; jt < 4; ++jt) {
        const int j = jt * 16 + s;
        bias[jt] = b3[j];
        B0[jt].i[0] = cvt_pk_bf16(W3[( 4*q+0)*64+j], W3[( 4*q+1)*64+j]);
        B0[jt].i[1] = cvt_pk_bf16(W3[( 4*q+2)*64+j], W3[( 4*q+3)*64+j]);
        B0[jt].i[2] = cvt_pk_bf16(W3[(16+4*q+0)*64+j], W3[(16+4*q+1)*64+j]);
        B0[jt].i[3] = cvt_pk_bf16(W3[(16+4*q+2)*64+j], W3[(16+4*q+3)*64+j]);
        B1[jt].i[0] = cvt_pk_bf16(W3[(32+4*q+0)*64+j], W3[(32+4*q+1)*64+j]);
        B1[jt].i[1] = cvt_pk_bf16(W3[(32+4*q+2)*64+j], W3[(32+4*q+3)*64+j]);
        B1[jt].i[2] = cvt_pk_bf16(W3[(48+4*q+0)*64+j], W3[(48+4*q+1)*64+j]);
        B1[jt].i[3] = cvt_pk_bf16(W3[(48+4*q+2)*64+j], W3[(48+4*q+3)*64+j]);
    }
    const f32x4 zero4 = {0.f, 0.f, 0.f, 0.f};

    for (int tile = blockIdx.x * 4 + wv; tile < ntiles; tile += totwaves) {
        const long base = (long)tile * 16;

        const long row_i = base + s;
        const long row_c = row_i < n_out ? row_i : n_out - 1;
        const float* row = agg + row_c * 64;
        const int dd = start[row_c + 1] - start[row_c];
        const float invd = 1.0f / (float)(dd > 0 ? dd : 1);

        f32x4 r0 = *(const f32x4*)(row +      4*q);
        f32x4 r1 = *(const f32x4*)(row + 16 + 4*q);
        f32x4 r2 = *(const f32x4*)(row + 32 + 4*q);
        f32x4 r3 = *(const f32x4*)(row + 48 + 4*q);
        r0 *= invd; r1 *= invd; r2 *= invd; r3 *= invd;

        frag_u A0, A1;
        A0.i[0] = cvt_pk_bf16(r0.x, r0.y); A0.i[1] = cvt_pk_bf16(r0.z, r0.w);
        A0.i[2] = cvt_pk_bf16(r1.x, r1.y); A0.i[3] = cvt_pk_bf16(r1.z, r1.w);
        A1.i[0] = cvt_pk_bf16(r2.x, r2.y); A1.i[1] = cvt_pk_bf16(r2.z, r2.w);
        A1.i[2] = cvt_pk_bf16(r3.x, r3.y); A1.i[3] = cvt_pk_bf16(r3.z, r3.w);

#pragma unroll
        for (int jt = 0; jt < 4; ++jt) {
            f32x4 d = __builtin_amdgcn_mfma_f32_16x16x32_bf16(A0.v, B0[jt].v, zero4, 0, 0, 0);
            d = __builtin_amdgcn_mfma_f32_16x16x32_bf16(A1.v, B1[jt].v, d, 0, 0, 0);
            const int j = jt * 16 + s;
#pragma unroll
            for (int r = 0; r < 4; ++r) {
                const long nodei = base + 4*q + r;
                if (nodei < n_out) {
                    float v = d[r] + bias[jt];
                    if (isnan(v)) v = 0.0f;
                    else if (isinf(v)) v = (v > 0.0f) ? 1e6f : -1e6f;
                    agg[nodei * 64 + j] = v;
                }
            }
        }
    }
}

extern "C" void kernel_launch(void* const* d_in, const int* in_sizes, int n_in_args,
                              void* d_out, int out_size, void* d_ws, size_t ws_size,
                              hipStream_t stream) {
    const float* x_in      = (const float*)d_in[0];
    const float* pos_in    = (const float*)d_in[1];
    // d_in[2] = batch_in (unused)
    const float* pos_out   = (const float*)d_in[3];
    const int*   in_index  = (const int*)d_in[4];
    const int*   out_index = (const int*)d_in[5];
    const float* W1        = (const float*)d_in[6];
    const float* W2        = (const float*)d_in[7];
    const float* W3        = (const float*)d_in[8];
    const float* b3        = (const float*)d_in[9];
    float* out = (float*)d_out;

    const int n_out = in_sizes[3] / 3;   // pos_out is [N_OUT, 3]
    const int E     = in_sizes[4];
    const int n_in  = in_sizes[0];       // x_in is [N_IN, 1]

    // ws layout: start[n_out+1] | pos4[n_in] | pos_out4[n_out] (tiered)
    int* start = (int*)d_ws;
    const size_t start_bytes = ((size_t)(n_out + 1) * 4 + 255) & ~(size_t)255;
    const size_t need1 = start_bytes + (size_t)n_in * 16;
    const size_t need2 = need1 + (size_t)n_out * 16;
    const int tier = (ws_size >= need2) ? 2 : (ws_size >= need1 ? 1 : 0);
    f32x4* pos4    = tier >= 1 ? (f32x4*)((char*)d_ws + start_bytes) : nullptr;
    f32x4* pos_out4= tier >= 2 ? (f32x4*)((char*)d_ws + need1) : nullptr;

    {
        const int nzero4 = n_out * 16;                  // n_out*64 floats / 4
        int span = (E + 1) > nzero4 ? (E + 1) : nzero4;
        if (n_in > span) span = n_in;
        dim3 b(256), g((span + 255) / 256);
        k_zero_start<<<g, b, 0, stream>>>(out_index, start, (f32x4*)out, n_out, E,
                                          nzero4, pos_in, x_in, pos4, n_in,
                                          pos_out, pos_out4);
    }

    {
        const int nwin = (E + 63) / 64;              // 64 edges per window
        const int nblocks = (nwin + 3) / 4;          // ONE window per wave
        const int totwaves = nblocks * 4;
        if (tier == 2)
            k_edges<2><<<dim3(nblocks), dim3(256), 0, stream>>>(
                x_in, pos_in, pos4, pos_out4, pos_out, in_index, out_index, W1, W2, out, E, nwin, totwaves);
        else if (tier == 1)
            k_edges<1><<<dim3(nblocks), dim3(256), 0, stream>>>(
                x_in, pos_in, pos4, pos_out4, pos_out, in_index, out_index, W1, W2, out, E, nwin, totwaves);
        else
            k_edges<0><<<dim3(nblocks), dim3(256), 0, stream>>>(
                x_in, pos_in, pos4, pos_out4, pos_out, in_index, out_index, W1, W2, out, E, nwin, totwaves);
    }
    {
        const int ntiles = (n_out + 15) / 16;        // 16 nodes per tile
        const int nblocks = (ntiles + 7) / 8;        // ~2 tiles per wave
        const int totwaves = nblocks * 4;
        k_out<<<dim3(nblocks), dim3(256), 0, stream>>>(
            out, W3, b3, start, n_out, ntiles, totwaves);
    }
}

// Round 15
// 66.449 us; speedup vs baseline: 1.6962x; 1.0672x over previous
//
#include <hip/hip_runtime.h>
#include <math.h>

// PointConv round 15: r14 verbatim + __launch_bounds__(256,4) on k_edges.
//   Theory: occupancy is capped ~11 waves/CU by hidden AGPR allocation
//   (unified gfx950 reg file; CSV VGPR_Count excludes acc regs). Forcing
//   min 4 waves/EU caps total regs at 128/wave -> 16 waves/CU minimum.
//   Everything else identical to round 14 (70.9us verified).

typedef __attribute__((ext_vector_type(8))) short short8;
typedef __attribute__((ext_vector_type(4))) float f32x4;
typedef __attribute__((ext_vector_type(4))) int   int4v;
typedef __attribute__((ext_vector_type(2))) int   int2v;

union frag_u { int i[4]; short8 v; };

__device__ __forceinline__ float celu1(float x) {
    float m = fminf(x, 0.0f);
    return fmaxf(x, __expf(m) - 1.0f);
}
__device__ __forceinline__ int cvt_pk_bf16(float lo, float hi) {
    int r; asm("v_cvt_pk_bf16_f32 %0, %1, %2" : "=v"(r) : "v"(lo), "v"(hi)); return r;
}

// start[o]=lower_bound(out_index,o); zero agg; pack pos4[i]={pos_in[i],x_in[i]},
// pos_out4[o]={pos_out[o],0}
__global__ void k_zero_start(const int* __restrict__ oi, int* __restrict__ start,
                             f32x4* __restrict__ agg4, int n_out, int E, int nzero4,
                             const float* __restrict__ pos_in,
                             const float* __restrict__ x_in,
                             f32x4* __restrict__ pos4, int n_in,
                             const float* __restrict__ pos_out,
                             f32x4* __restrict__ pos_out4) {
    const int t = blockIdx.x * blockDim.x + threadIdx.x;
    if (t <= E) {
        const int cur  = (t < E) ? oi[t] : n_out;
        const int prev = (t > 0) ? oi[t - 1] : -1;
        for (int o = prev + 1; o <= cur; ++o) start[o] = t;
    }
    if (pos4 != nullptr && t < n_in) {
        f32x4 v;
        v.x = pos_in[t*3+0]; v.y = pos_in[t*3+1]; v.z = pos_in[t*3+2];
        v.w = x_in[t];
        pos4[t] = v;
    }
    if (pos_out4 != nullptr && t < n_out) {
        f32x4 v;
        v.x = pos_out[t*3+0]; v.y = pos_out[t*3+1]; v.z = pos_out[t*3+2];
        v.w = 0.0f;
        pos_out4[t] = v;
    }
    const f32x4 z = {0.f, 0.f, 0.f, 0.f};
    for (int i = t; i < nzero4; i += gridDim.x * blockDim.x) agg4[i] = z;
}

template<int TIER>
__global__ __launch_bounds__(256, 4) void k_edges(
    const float* __restrict__ x_in, const float* __restrict__ pos_in,
    const f32x4* __restrict__ pos4, const f32x4* __restrict__ pos_out4,
    const float* __restrict__ pos_out, const int* __restrict__ in_index,
    const int* __restrict__ out_index,
    const float* __restrict__ W1, const float* __restrict__ W2,
    float* __restrict__ agg, int E, int nwin, int totwaves)
{
    __shared__ int   hbuf [4][64][10];   // padded rows (40B) -> conflict-light reads
    __shared__ float scoef[4][64];
    __shared__ int   srank[4][64];       // window-rank (fast) or quarter-rank (fallback)
    __shared__ int   snid [4][64];       // quarter-rank node ids (fallback path)
    __shared__ int   snidw[4][16];       // window-rank node ids (fast path)

    const int wv = threadIdx.x >> 6, lane = threadIdx.x & 63;
    const int kcol = lane & 15, q = lane >> 4;

    // B1 = W2 fragments: B[kk=4q+i][n=j=jt*16+kcol], K upper half zero
    frag_u b1[4];
#pragma unroll
    for (int jt = 0; jt < 4; ++jt) {
        const int j = jt * 16 + kcol;
        b1[jt].i[0] = cvt_pk_bf16(W2[(4*q+0)*64 + j], W2[(4*q+1)*64 + j]);
        b1[jt].i[1] = cvt_pk_bf16(W2[(4*q+2)*64 + j], W2[(4*q+3)*64 + j]);
        b1[jt].i[2] = 0; b1[jt].i[3] = 0;
    }
    const f32x4 zero4 = {0.f, 0.f, 0.f, 0.f};

    for (int win = blockIdx.x * 4 + wv; win < nwin; win += totwaves) {
        const int e = win * 64 + lane;
        const bool valid = e < E;
        const int ec = valid ? e : E - 1;

        const int node = out_index[ec];
        const int idx  = in_index[ec];

        float xv, pix, piy, piz;
        if (TIER >= 1) {
            const f32x4 pv = pos4[idx];          // ONE scattered 16B gather
            pix = pv.x; piy = pv.y; piz = pv.z; xv = pv.w;
        } else {
            xv  = x_in[idx];
            pix = pos_in[idx*3+0]; piy = pos_in[idx*3+1]; piz = pos_in[idx*3+2];
        }
        float pox, poy, poz;
        if (TIER >= 2) {
            const f32x4 po = pos_out4[node];     // ONE 16B (mostly-broadcast) load
            pox = po.x; poy = po.y; poz = po.z;
        } else {
            pox = pos_out[node*3+0]; poy = pos_out[node*3+1]; poz = pos_out[node*3+2];
        }
        const float coef = valid ? xv : 0.0f;    // unnormalized; deg in k_out
        const float px = pix - pox;
        const float py = piy - poy;
        const float pz = piz - poz;

        // this lane's edge: all 16 h channels
        int hp[8];
#pragma unroll
        for (int c = 0; c < 8; ++c) {
            const float h0 = celu1(fmaf(pz, W1[32 + 2*c],     fmaf(py, W1[16 + 2*c],     px * W1[2*c])));
            const float h1 = celu1(fmaf(pz, W1[32 + 2*c + 1], fmaf(py, W1[16 + 2*c + 1], px * W1[2*c + 1])));
            hp[c] = cvt_pk_bf16(h0, h1);
        }
        *(int4v*)&hbuf[wv][lane][0] = *(const int4v*)&hp[0];
        *(int4v*)&hbuf[wv][lane][4] = *(const int4v*)&hp[4];

        // ---- window-level segmentation ----
        const int prevn = __shfl_up(node, 1);
        const bool whead = (lane == 0) || (node != prevn);
        const unsigned long long wbal = __ballot(whead);
        const int ndw = __popcll(wbal);

        scoef[wv][lane] = coef;

        if (ndw <= 16) {
            // ======== fast path: window-rank MFMA2, D2 accumulated in registers ========
            const int wrank = __popcll(wbal & ((2ULL << lane) - 1)) - 1;
            srank[wv][lane] = wrank;
            if (whead) snidw[wv][wrank] = node;

            f32x4 d2acc[4] = {zero4, zero4, zero4, zero4};

#pragma unroll
            for (int Q = 0; Q < 4; ++Q) {
                const int2v a1lo = *(const int2v*)&hbuf[wv][Q*16 + kcol][2*q];
                frag_u a1; a1.i[0] = a1lo.x; a1.i[1] = a1lo.y; a1.i[2] = 0; a1.i[3] = 0;

                const f32x4 c4 = *(const f32x4*)&scoef[wv][Q*16 + 4*q];
                const int4v r4 = *(const int4v*)&srank[wv][Q*16 + 4*q];

                frag_u a2;
                a2.i[0] = cvt_pk_bf16(r4.x == kcol ? c4.x : 0.0f, r4.y == kcol ? c4.y : 0.0f);
                a2.i[1] = cvt_pk_bf16(r4.z == kcol ? c4.z : 0.0f, r4.w == kcol ? c4.w : 0.0f);
                a2.i[2] = 0; a2.i[3] = 0;

#pragma unroll
                for (int jt = 0; jt < 4; ++jt) {
                    f32x4 d1 = __builtin_amdgcn_mfma_f32_16x16x32_bf16(a1.v, b1[jt].v, zero4, 0, 0, 0);
                    frag_u b2;
                    b2.i[0] = cvt_pk_bf16(celu1(d1[0]), celu1(d1[1]));
                    b2.i[1] = cvt_pk_bf16(celu1(d1[2]), celu1(d1[3]));
                    b2.i[2] = 0; b2.i[3] = 0;
                    d2acc[jt] = __builtin_amdgcn_mfma_f32_16x16x32_bf16(a2.v, b2.v, d2acc[jt], 0, 0, 0);
                }
            }

            // ONE atomic phase per window
            const int4v n4 = *(const int4v*)&snidw[wv][4*q & 15];
            float* p0 = agg + (long)n4.x * 64 + kcol;
            float* p1 = agg + (long)n4.y * 64 + kcol;
            float* p2 = agg + (long)n4.z * 64 + kcol;
            float* p3 = agg + (long)n4.w * 64 + kcol;
#pragma unroll
            for (int jt = 0; jt < 4; ++jt) {
                if (4*q + 0 < ndw) unsafeAtomicAdd(p0 + jt * 16, d2acc[jt][0]);
                if (4*q + 1 < ndw) unsafeAtomicAdd(p1 + jt * 16, d2acc[jt][1]);
                if (4*q + 2 < ndw) unsafeAtomicAdd(p2 + jt * 16, d2acc[jt][2]);
                if (4*q + 3 < ndw) unsafeAtomicAdd(p3 + jt * 16, d2acc[jt][3]);
            }
        } else {
            // ======== fallback: verbatim r9 quarter-atomic path ========
            const unsigned long long qbal = wbal | 0x0001000100010001ULL;
            const unsigned mym = (unsigned)(qbal >> (q * 16)) & 0xFFFFu;
            const int rank = __popc(mym & ((2u << kcol) - 1)) - 1;
            srank[wv][lane] = rank;
            const bool qhead = (qbal >> lane) & 1ull;
            if (qhead) snid[wv][(lane & 48) + rank] = node;

            int ndq[4];
#pragma unroll
            for (int Q = 0; Q < 4; ++Q) ndq[Q] = __popc((unsigned)(qbal >> (Q * 16)) & 0xFFFFu);

#pragma unroll
            for (int Q = 0; Q < 4; ++Q) {
                const int2v a1lo = *(const int2v*)&hbuf[wv][Q*16 + kcol][2*q];
                frag_u a1; a1.i[0] = a1lo.x; a1.i[1] = a1lo.y; a1.i[2] = 0; a1.i[3] = 0;

                const f32x4 c4 = *(const f32x4*)&scoef[wv][Q*16 + 4*q];
                const int4v r4 = *(const int4v*)&srank[wv][Q*16 + 4*q];
                const int4v n4 = *(const int4v*)&snid [wv][Q*16 + 4*q];

                frag_u a2;
                a2.i[0] = cvt_pk_bf16(r4.x == kcol ? c4.x : 0.0f, r4.y == kcol ? c4.y : 0.0f);
                a2.i[1] = cvt_pk_bf16(r4.z == kcol ? c4.z : 0.0f, r4.w == kcol ? c4.w : 0.0f);
                a2.i[2] = 0; a2.i[3] = 0;

                const int nd = ndq[Q];
                float* p0 = agg + (long)n4.x * 64 + kcol;
                float* p1 = agg + (long)n4.y * 64 + kcol;
                float* p2 = agg + (long)n4.z * 64 + kcol;
                float* p3 = agg + (long)n4.w * 64 + kcol;

#pragma unroll
                for (int jt = 0; jt < 4; ++jt) {
                    f32x4 d1 = __builtin_amdgcn_mfma_f32_16x16x32_bf16(a1.v, b1[jt].v, zero4, 0, 0, 0);
                    frag_u b2;
                    b2.i[0] = cvt_pk_bf16(celu1(d1[0]), celu1(d1[1]));
                    b2.i[1] = cvt_pk_bf16(celu1(d1[2]), celu1(d1[3]));
                    b2.i[2] = 0; b2.i[3] = 0;
                    f32x4 d2 = __builtin_amdgcn_mfma_f32_16x16x32_bf16(a2.v, b2.v, zero4, 0, 0, 0);
                    if (4*q + 0 < nd) unsafeAtomicAdd(p0 + jt * 16, d2[0]);
                    if (4*q + 1 < nd) unsafeAtomicAdd(p1 + jt * 16, d2[1]);
                    if (4*q + 2 < nd) unsafeAtomicAdd(p2 + jt * 16, d2[2]);
                    if (4*q + 3 < nd) unsafeAtomicAdd(p3 + jt * 16, d2[3]);
                }
            }
        }
    }
}

__global__ __launch_bounds__(256) void k_out(
    float* __restrict__ agg, const float* __restrict__ W3,
    const float* __restrict__ b3, const int* __restrict__ start,
    int n_out, int ntiles, int totwaves)
{
    const int wv = threadIdx.x >> 6, lane = threadIdx.x & 63;
    const int s = lane & 15, q = lane >> 4;

    frag_u B0[4], B1[4];
    float bias[4];
#pragma unroll
    for (int jt = 0; jt < 4; ++jt) {
        const int j = jt * 16 + s;
        bias[jt] = b3[j];
        B0[jt].i[0] = cvt_pk_bf16(W3[( 4*q+0)*64+j], W3[( 4*q+1)*64+j]);
        B0[jt].i[1] = cvt_pk_bf16(W3[( 4*q+2)*64+j], W3[( 4*q+3)*64+j]);
        B0[jt].i[2] = cvt_pk_bf16(W3[(16+4*q+0)*64+j], W3[(16+4*q+1)*64+j]);
        B0[jt].i[3] = cvt_pk_bf16(W3[(16+4*q+2)*64+j], W3[(16+4*q+3)*64+j]);
        B1[jt].i[0] = cvt_pk_bf16(W3[(32+4*q+0)*64+j], W3[(32+4*q+1)*64+j]);
        B1[jt].i[1] = cvt_pk_bf16(W3[(32+4*q+2)*64+j], W3[(32+4*q+3)*64+j]);
        B1[jt].i[2] = cvt_pk_bf16(W3[(48+4*q+0)*64+j], W3[(48+4*q+1)*64+j]);
        B1[jt].i[3] = cvt_pk_bf16(W3[(48+4*q+2)*64+j], W3[(48+4*q+3)*64+j]);
    }
    const f32x4 zero4 = {0.f, 0.f, 0.f, 0.f};

    for (int tile = blockIdx.x * 4 + wv; tile < ntiles; tile += totwaves) {
        const long base = (long)tile * 16;

        const long row_i = base + s;
        const long row_c = row_i < n_out ? row_i : n_out - 1;
        const float* row = agg + row_c * 64;
        const int dd = start[row_c + 1] - start[row_c];
        const float invd = 1.0f / (float)(dd > 0 ? dd : 1);

        f32x4 r0 = *(const f32x4*)(row +      4*q);
        f32x4 r1 = *(const f32x4*)(row + 16 + 4*q);
        f32x4 r2 = *(const f32x4*)(row + 32 + 4*q);
        f32x4 r3 = *(const f32x4*)(row + 48 + 4*q);
        r0 *= invd; r1 *= invd; r2 *= invd; r3 *= invd;

        frag_u A0, A1;
        A0.i[0] = cvt_pk_bf16(r0.x, r0.y); A0.i[1] = cvt_pk_bf16(r0.z, r0.w);
        A0.i[2] = cvt_pk_bf16(r1.x, r1.y); A0.i[3] = cvt_pk_bf16(r1.z, r1.w);
        A1.i[0] = cvt_pk_bf16(r2.x, r2.y); A1.i[1] = cvt_pk_bf16(r2.z, r2.w);
        A1.i[2] = cvt_pk_bf16(r3.x, r3.y); A1.i[3] = cvt_pk_bf16(r3.z, r3.w);

#pragma unroll
        for (int jt = 0; jt < 4; ++jt) {
            f32x4 d = __builtin_amdgcn_mfma_f32_16x16x32_bf16(A0.v, B0[jt].v, zero4, 0, 0, 0);
            d = __builtin_amdgcn_mfma_f32_16x16x32_bf16(A1.v, B1[jt].v, d, 0, 0, 0);
            const int j = jt * 16 + s;
#pragma unroll
            for (int r = 0; r < 4; ++r) {
                const long nodei = base + 4*q + r;
                if (nodei < n_out) {
                    float v = d[r] + bias[jt];
                    if (isnan(v)) v = 0.0f;
                    else if (isinf(v)) v = (v > 0.0f) ? 1e6f : -1e6f;
                    agg[nodei * 64 + j] = v;
                }
            }
        }
    }
}

extern "C" void kernel_launch(void* const* d_in, const int* in_sizes, int n_in_args,
                              void* d_out, int out_size, void* d_ws, size_t ws_size,
                              hipStream_t stream) {
    const float* x_in      = (const float*)d_in[0];
    const float* pos_in    = (const float*)d_in[1];
    // d_in[2] = batch_in (unused)
    const float* pos_out   = (const float*)d_in[3];
    const int*   in_index  = (const int*)d_in[4];
    const int*   out_index = (const int*)d_in[5];
    const float* W1        = (const float*)d_in[6];
    const float* W2        = (const float*)d_in[7];
    const float* W3        = (const float*)d_in[8];
    const float* b3        = (const float*)d_in[9];
    float* out = (float*)d_out;

    const int n_out = in_sizes[3] / 3;   // pos_out is [N_OUT, 3]
    const int E     = in_sizes[4];
    const int n_in  = in_sizes[0];       // x_in is [N_IN, 1]

    // ws layout: start[n_out+1] | pos4[n_in] | pos_out4[n_out] (tiered)
    int* start = (int*)d_ws;
    const size_t start_bytes = ((size_t)(n_out + 1) * 4 + 255) & ~(size_t)255;
    const size_t need1 = start_bytes + (size_t)n_in * 16;
    const size_t need2 = need1 + (size_t)n_out * 16;
    const int tier = (ws_size >= need2) ? 2 : (ws_size >= need1 ? 1 : 0);
    f32x4* pos4    = tier >= 1 ? (f32x4*)((char*)d_ws + start_bytes) : nullptr;
    f32x4* pos_out4= tier >= 2 ? (f32x4*)((char*)d_ws + need1) : nullptr;

    {
        const int nzero4 = n_out * 16;                  // n_out*64 floats / 4
        int span = (E + 1) > nzero4 ? (E + 1) : nzero4;
        if (n_in > span) span = n_in;
        dim3 b(256), g((span + 255) / 256);
        k_zero_start<<<g, b, 0, stream>>>(out_index, start, (f32x4*)out, n_out, E,
                                          nzero4, pos_in, x_in, pos4, n_in,
                                          pos_out, pos_out4);
    }

    {
        const int nwin = (E + 63) / 64;              // 64 edges per window
        const int nblocks = (nwin + 3) / 4;          // ONE window per wave
        const int totwaves = nblocks * 4;
        if (tier == 2)
            k_edges<2><<<dim3(nblocks), dim3(256), 0, stream>>>(
                x_in, pos_in, pos4, pos_out4, pos_out, in_index, out_index, W1, W2, out, E, nwin, totwaves);
        else if (tier == 1)
            k_edges<1><<<dim3(nblocks), dim3(256), 0, stream>>>(
                x_in, pos_in, pos4, pos_out4, pos_out, in_index, out_index, W1, W2, out, E, nwin, totwaves);
        else
            k_edges<0><<<dim3(nblocks), dim3(256), 0, stream>>>(
                x_in, pos_in, pos4, pos_out4, pos_out, in_index, out_index, W1, W2, out, E, nwin, totwaves);
    }
    {
        const int ntiles = (n_out + 15) / 16;        // 16 nodes per tile
        const int nblocks = (ntiles + 7) / 8;        // ~2 tiles per wave
        const int totwaves = nblocks * 4;
        k_out<<<dim3(nblocks), dim3(256), 0, stream>>>(
            out, W3, b3, start, n_out, ntiles, totwaves);
    }
}

// Round 16
// 66.137 us; speedup vs baseline: 1.7042x; 1.0047x over previous
//
#include <hip/hip_runtime.h>
#include <math.h>

// PointConv round 16: r15 verbatim + tightened __launch_bounds__(256,6) on k_edges.
//   r15 confirmed the occupancy lever: (256,4) -> occupancy 34->41%, k_edges
//   49.8->44.6us, near-linear scaling. LDS (13.8KB) permits 11 blocks/CU, so
//   registers are the only cap: force >=6 waves/EU (<=85 regs/wave total).
//   Everything else identical to round 15 (66.4us verified).

typedef __attribute__((ext_vector_type(8))) short short8;
typedef __attribute__((ext_vector_type(4))) float f32x4;
typedef __attribute__((ext_vector_type(4))) int   int4v;
typedef __attribute__((ext_vector_type(2))) int   int2v;

union frag_u { int i[4]; short8 v; };

__device__ __forceinline__ float celu1(float x) {
    float m = fminf(x, 0.0f);
    return fmaxf(x, __expf(m) - 1.0f);
}
__device__ __forceinline__ int cvt_pk_bf16(float lo, float hi) {
    int r; asm("v_cvt_pk_bf16_f32 %0, %1, %2" : "=v"(r) : "v"(lo), "v"(hi)); return r;
}

// start[o]=lower_bound(out_index,o); zero agg; pack pos4[i]={pos_in[i],x_in[i]},
// pos_out4[o]={pos_out[o],0}
__global__ void k_zero_start(const int* __restrict__ oi, int* __restrict__ start,
                             f32x4* __restrict__ agg4, int n_out, int E, int nzero4,
                             const float* __restrict__ pos_in,
                             const float* __restrict__ x_in,
                             f32x4* __restrict__ pos4, int n_in,
                             const float* __restrict__ pos_out,
                             f32x4* __restrict__ pos_out4) {
    const int t = blockIdx.x * blockDim.x + threadIdx.x;
    if (t <= E) {
        const int cur  = (t < E) ? oi[t] : n_out;
        const int prev = (t > 0) ? oi[t - 1] : -1;
        for (int o = prev + 1; o <= cur; ++o) start[o] = t;
    }
    if (pos4 != nullptr && t < n_in) {
        f32x4 v;
        v.x = pos_in[t*3+0]; v.y = pos_in[t*3+1]; v.z = pos_in[t*3+2];
        v.w = x_in[t];
        pos4[t] = v;
    }
    if (pos_out4 != nullptr && t < n_out) {
        f32x4 v;
        v.x = pos_out[t*3+0]; v.y = pos_out[t*3+1]; v.z = pos_out[t*3+2];
        v.w = 0.0f;
        pos_out4[t] = v;
    }
    const f32x4 z = {0.f, 0.f, 0.f, 0.f};
    for (int i = t; i < nzero4; i += gridDim.x * blockDim.x) agg4[i] = z;
}

template<int TIER>
__global__ __launch_bounds__(256, 6) void k_edges(
    const float* __restrict__ x_in, const float* __restrict__ pos_in,
    const f32x4* __restrict__ pos4, const f32x4* __restrict__ pos_out4,
    const float* __restrict__ pos_out, const int* __restrict__ in_index,
    const int* __restrict__ out_index,
    const float* __restrict__ W1, const float* __restrict__ W2,
    float* __restrict__ agg, int E, int nwin, int totwaves)
{
    __shared__ int   hbuf [4][64][10];   // padded rows (40B) -> conflict-light reads
    __shared__ float scoef[4][64];
    __shared__ int   srank[4][64];       // window-rank (fast) or quarter-rank (fallback)
    __shared__ int   snid [4][64];       // quarter-rank node ids (fallback path)
    __shared__ int   snidw[4][16];       // window-rank node ids (fast path)

    const int wv = threadIdx.x >> 6, lane = threadIdx.x & 63;
    const int kcol = lane & 15, q = lane >> 4;

    // B1 = W2 fragments: B[kk=4q+i][n=j=jt*16+kcol], K upper half zero
    frag_u b1[4];
#pragma unroll
    for (int jt = 0; jt < 4; ++jt) {
        const int j = jt * 16 + kcol;
        b1[jt].i[0] = cvt_pk_bf16(W2[(4*q+0)*64 + j], W2[(4*q+1)*64 + j]);
        b1[jt].i[1] = cvt_pk_bf16(W2[(4*q+2)*64 + j], W2[(4*q+3)*64 + j]);
        b1[jt].i[2] = 0; b1[jt].i[3] = 0;
    }
    const f32x4 zero4 = {0.f, 0.f, 0.f, 0.f};

    for (int win = blockIdx.x * 4 + wv; win < nwin; win += totwaves) {
        const int e = win * 64 + lane;
        const bool valid = e < E;
        const int ec = valid ? e : E - 1;

        const int node = out_index[ec];
        const int idx  = in_index[ec];

        float xv, pix, piy, piz;
        if (TIER >= 1) {
            const f32x4 pv = pos4[idx];          // ONE scattered 16B gather
            pix = pv.x; piy = pv.y; piz = pv.z; xv = pv.w;
        } else {
            xv  = x_in[idx];
            pix = pos_in[idx*3+0]; piy = pos_in[idx*3+1]; piz = pos_in[idx*3+2];
        }
        float pox, poy, poz;
        if (TIER >= 2) {
            const f32x4 po = pos_out4[node];     // ONE 16B (mostly-broadcast) load
            pox = po.x; poy = po.y; poz = po.z;
        } else {
            pox = pos_out[node*3+0]; poy = pos_out[node*3+1]; poz = pos_out[node*3+2];
        }
        const float coef = valid ? xv : 0.0f;    // unnormalized; deg in k_out
        const float px = pix - pox;
        const float py = piy - poy;
        const float pz = piz - poz;

        // this lane's edge: all 16 h channels
        int hp[8];
#pragma unroll
        for (int c = 0; c < 8; ++c) {
            const float h0 = celu1(fmaf(pz, W1[32 + 2*c],     fmaf(py, W1[16 + 2*c],     px * W1[2*c])));
            const float h1 = celu1(fmaf(pz, W1[32 + 2*c + 1], fmaf(py, W1[16 + 2*c + 1], px * W1[2*c + 1])));
            hp[c] = cvt_pk_bf16(h0, h1);
        }
        *(int4v*)&hbuf[wv][lane][0] = *(const int4v*)&hp[0];
        *(int4v*)&hbuf[wv][lane][4] = *(const int4v*)&hp[4];

        // ---- window-level segmentation ----
        const int prevn = __shfl_up(node, 1);
        const bool whead = (lane == 0) || (node != prevn);
        const unsigned long long wbal = __ballot(whead);
        const int ndw = __popcll(wbal);

        scoef[wv][lane] = coef;

        if (ndw <= 16) {
            // ======== fast path: window-rank MFMA2, D2 accumulated in registers ========
            const int wrank = __popcll(wbal & ((2ULL << lane) - 1)) - 1;
            srank[wv][lane] = wrank;
            if (whead) snidw[wv][wrank] = node;

            f32x4 d2acc[4] = {zero4, zero4, zero4, zero4};

#pragma unroll
            for (int Q = 0; Q < 4; ++Q) {
                const int2v a1lo = *(const int2v*)&hbuf[wv][Q*16 + kcol][2*q];
                frag_u a1; a1.i[0] = a1lo.x; a1.i[1] = a1lo.y; a1.i[2] = 0; a1.i[3] = 0;

                const f32x4 c4 = *(const f32x4*)&scoef[wv][Q*16 + 4*q];
                const int4v r4 = *(const int4v*)&srank[wv][Q*16 + 4*q];

                frag_u a2;
                a2.i[0] = cvt_pk_bf16(r4.x == kcol ? c4.x : 0.0f, r4.y == kcol ? c4.y : 0.0f);
                a2.i[1] = cvt_pk_bf16(r4.z == kcol ? c4.z : 0.0f, r4.w == kcol ? c4.w : 0.0f);
                a2.i[2] = 0; a2.i[3] = 0;

#pragma unroll
                for (int jt = 0; jt < 4; ++jt) {
                    f32x4 d1 = __builtin_amdgcn_mfma_f32_16x16x32_bf16(a1.v, b1[jt].v, zero4, 0, 0, 0);
                    frag_u b2;
                    b2.i[0] = cvt_pk_bf16(celu1(d1[0]), celu1(d1[1]));
                    b2.i[1] = cvt_pk_bf16(celu1(d1[2]), celu1(d1[3]));
                    b2.i[2] = 0; b2.i[3] = 0;
                    d2acc[jt] = __builtin_amdgcn_mfma_f32_16x16x32_bf16(a2.v, b2.v, d2acc[jt], 0, 0, 0);
                }
            }

            // ONE atomic phase per window
            const int4v n4 = *(const int4v*)&snidw[wv][4*q & 15];
            float* p0 = agg + (long)n4.x * 64 + kcol;
            float* p1 = agg + (long)n4.y * 64 + kcol;
            float* p2 = agg + (long)n4.z * 64 + kcol;
            float* p3 = agg + (long)n4.w * 64 + kcol;
#pragma unroll
            for (int jt = 0; jt < 4; ++jt) {
                if (4*q + 0 < ndw) unsafeAtomicAdd(p0 + jt * 16, d2acc[jt][0]);
                if (4*q + 1 < ndw) unsafeAtomicAdd(p1 + jt * 16, d2acc[jt][1]);
                if (4*q + 2 < ndw) unsafeAtomicAdd(p2 + jt * 16, d2acc[jt][2]);
                if (4*q + 3 < ndw) unsafeAtomicAdd(p3 + jt * 16, d2acc[jt][3]);
            }
        } else {
            // ======== fallback: verbatim r9 quarter-atomic path ========
            const unsigned long long qbal = wbal | 0x0001000100010001ULL;
            const unsigned mym = (unsigned)(qbal >> (q * 16)) & 0xFFFFu;
            const int rank = __popc(mym & ((2u << kcol) - 1)) - 1;
            srank[wv][lane] = rank;
            const bool qhead = (qbal >> lane) & 1ull;
            if (qhead) snid[wv][(lane & 48) + rank] = node;

            int ndq[4];
#pragma unroll
            for (int Q = 0; Q < 4; ++Q) ndq[Q] = __popc((unsigned)(qbal >> (Q * 16)) & 0xFFFFu);

#pragma unroll
            for (int Q = 0; Q < 4; ++Q) {
                const int2v a1lo = *(const int2v*)&hbuf[wv][Q*16 + kcol][2*q];
                frag_u a1; a1.i[0] = a1lo.x; a1.i[1] = a1lo.y; a1.i[2] = 0; a1.i[3] = 0;

                const f32x4 c4 = *(const f32x4*)&scoef[wv][Q*16 + 4*q];
                const int4v r4 = *(const int4v*)&srank[wv][Q*16 + 4*q];
                const int4v n4 = *(const int4v*)&snid [wv][Q*16 + 4*q];

                frag_u a2;
                a2.i[0] = cvt_pk_bf16(r4.x == kcol ? c4.x : 0.0f, r4.y == kcol ? c4.y : 0.0f);
                a2.i[1] = cvt_pk_bf16(r4.z == kcol ? c4.z : 0.0f, r4.w == kcol ? c4.w : 0.0f);
                a2.i[2] = 0; a2.i[3] = 0;

                const int nd = ndq[Q];
                float* p0 = agg + (long)n4.x * 64 + kcol;
                float* p1 = agg + (long)n4.y * 64 + kcol;
                float* p2 = agg + (long)n4.z * 64 + kcol;
                float* p3 = agg + (long)n4.w * 64 + kcol;

#pragma unroll
                for (int jt = 0; jt < 4; ++jt) {
                    f32x4 d1 = __builtin_amdgcn_mfma_f32_16x16x32_bf16(a1.v, b1[jt].v, zero4, 0, 0, 0);
                    frag_u b2;
                    b2.i[0] = cvt_pk_bf16(celu1(d1[0]), celu1(d1[1]));
                    b2.i[1] = cvt_pk_bf16(celu1(d1[2]), celu1(d1[3]));
                    b2.i[2] = 0; b2.i[3] = 0;
                    f32x4 d2 = __builtin_amdgcn_mfma_f32_16x16x32_bf16(a2.v, b2.v, zero4, 0, 0, 0);
                    if (4*q + 0 < nd) unsafeAtomicAdd(p0 + jt * 16, d2[0]);
                    if (4*q + 1 < nd) unsafeAtomicAdd(p1 + jt * 16, d2[1]);
                    if (4*q + 2 < nd) unsafeAtomicAdd(p2 + jt * 16, d2[2]);
                    if (4*q + 3 < nd) unsafeAtomicAdd(p3 + jt * 16, d2[3]);
                }
            }
        }
    }
}

__global__ __launch_bounds__(256) void k_out(
    float* __restrict__ agg, const float* __restrict__ W3,
    const float* __restrict__ b3, const int* __restrict__ start,
    int n_out, int ntiles, int totwaves)
{
    const int wv = threadIdx.x >> 6, lane = threadIdx.x & 63;
    const int s = lane & 15, q = lane >> 4;

    frag_u B0[4], B1[4];
    float bias[4];
#pragma unroll
    for (int jt = 0; jt < 4; ++jt) {
        const int j = jt * 16 + s;
        bias[jt] = b3[j];
        B0[jt].i[0] = cvt_pk_bf16(W3[( 4*q+0)*64+j], W3[( 4*q+1)*64+j]);
        B0[jt].i[1] = cvt_pk_bf16(W3[( 4*q+2)*64+j], W3[( 4*q+3)*64+j]);
        B0[jt].i[2] = cvt_pk_bf16(W3[(16+4*q+0)*64+j], W3[(16+4*q+1)*64+j]);
        B0[jt].i[3] = cvt_pk_bf16(W3[(16+4*q+2)*64+j], W3[(16+4*q+3)*64+j]);
        B1[jt].i[0] = cvt_pk_bf16(W3[(32+4*q+0)*64+j], W3[(32+4*q+1)*64+j]);
        B1[jt].i[1] = cvt_pk_bf16(W3[(32+4*q+2)*64+j], W3[(32+4*q+3)*64+j]);
        B1[jt].i[2] = cvt_pk_bf16(W3[(48+4*q+0)*64+j], W3[(48+4*q+1)*64+j]);
        B1[jt].i[3] = cvt_pk_bf16(W3[(48+4*q+2)*64+j], W3[(48+4*q+3)*64+j]);
    }
    const f32x4 zero4 = {0.f, 0.f, 0.f, 0.f};

    for (int tile = blockIdx.x * 4 + wv; tile < ntiles; tile += totwaves) {
        const long base = (long)tile * 16;

        const long row_i = base + s;
        const long row_c = row_i < n_out ? row_i : n_out - 1;
        const float* row = agg + row_c * 64;
        const int dd = start[row_c + 1] - start[row_c];
        const float invd = 1.0f / (float)(dd > 0 ? dd : 1);

        f32x4 r0 = *(const f32x4*)(row +      4*q);
        f32x4 r1 = *(const f32x4*)(row + 16 + 4*q);
        f32x4 r2 = *(const f32x4*)(row + 32 + 4*q);
        f32x4 r3 = *(const f32x4*)(row + 48 + 4*q);
        r0 *= invd; r1 *= invd; r2 *= invd; r3 *= invd;

        frag_u A0, A1;
        A0.i[0] = cvt_pk_bf16(r0.x, r0.y); A0.i[1] = cvt_pk_bf16(r0.z, r0.w);
        A0.i[2] = cvt_pk_bf16(r1.x, r1.y); A0.i[3] = cvt_pk_bf16(r1.z, r1.w);
        A1.i[0] = cvt_pk_bf16(r2.x, r2.y); A1.i[1] = cvt_pk_bf16(r2.z, r2.w);
        A1.i[2] = cvt_pk_bf16(r3.x, r3.y); A1.i[3] = cvt_pk_bf16(r3.z, r3.w);

#pragma unroll
        for (int jt = 0; jt < 4; ++jt) {
            f32x4 d = __builtin_amdgcn_mfma_f32_16x16x32_bf16(A0.v, B0[jt].v, zero4, 0, 0, 0);
            d = __builtin_amdgcn_mfma_f32_16x16x32_bf16(A1.v, B1[jt].v, d, 0, 0, 0);
            const int j = jt * 16 + s;
#pragma unroll
            for (int r = 0; r < 4; ++r) {
                const long nodei = base + 4*q + r;
                if (nodei < n_out) {
                    float v = d[r] + bias[jt];
                    if (isnan(v)) v = 0.0f;
                    else if (isinf(v)) v = (v > 0.0f) ? 1e6f : -1e6f;
                    agg[nodei * 64 + j] = v;
                }
            }
        }
    }
}

extern "C" void kernel_launch(void* const* d_in, const int* in_sizes, int n_in_args,
                              void* d_out, int out_size, void* d_ws, size_t ws_size,
                              hipStream_t stream) {
    const float* x_in      = (const float*)d_in[0];
    const float* pos_in    = (const float*)d_in[1];
    // d_in[2] = batch_in (unused)
    const float* pos_out   = (const float*)d_in[3];
    const int*   in_index  = (const int*)d_in[4];
    const int*   out_index = (const int*)d_in[5];
    const float* W1        = (const float*)d_in[6];
    const float* W2        = (const float*)d_in[7];
    const float* W3        = (const float*)d_in[8];
    const float* b3        = (const float*)d_in[9];
    float* out = (float*)d_out;

    const int n_out = in_sizes[3] / 3;   // pos_out is [N_OUT, 3]
    const int E     = in_sizes[4];
    const int n_in  = in_sizes[0];       // x_in is [N_IN, 1]

    // ws layout: start[n_out+1] | pos4[n_in] | pos_out4[n_out] (tiered)
    int* start = (int*)d_ws;
    const size_t start_bytes = ((size_t)(n_out + 1) * 4 + 255) & ~(size_t)255;
    const size_t need1 = start_bytes + (size_t)n_in * 16;
    const size_t need2 = need1 + (size_t)n_out * 16;
    const int tier = (ws_size >= need2) ? 2 : (ws_size >= need1 ? 1 : 0);
    f32x4* pos4    = tier >= 1 ? (f32x4*)((char*)d_ws + start_bytes) : nullptr;
    f32x4* pos_out4= tier >= 2 ? (f32x4*)((char*)d_ws + need1) : nullptr;

    {
        const int nzero4 = n_out * 16;                  // n_out*64 floats / 4
        int span = (E + 1) > nzero4 ? (E + 1) : nzero4;
        if (n_in > span) span = n_in;
        dim3 b(256), g((span + 255) / 256);
        k_zero_start<<<g, b, 0, stream>>>(out_index, start, (f32x4*)out, n_out, E,
                                          nzero4, pos_in, x_in, pos4, n_in,
                                          pos_out, pos_out4);
    }

    {
        const int nwin = (E + 63) / 64;              // 64 edges per window
        const int nblocks = (nwin + 3) / 4;          // ONE window per wave
        const int totwaves = nblocks * 4;
        if (tier == 2)
            k_edges<2><<<dim3(nblocks), dim3(256), 0, stream>>>(
                x_in, pos_in, pos4, pos_out4, pos_out, in_index, out_index, W1, W2, out, E, nwin, totwaves);
        else if (tier == 1)
            k_edges<1><<<dim3(nblocks), dim3(256), 0, stream>>>(
                x_in, pos_in, pos4, pos_out4, pos_out, in_index, out_index, W1, W2, out, E, nwin, totwaves);
        else
            k_edges<0><<<dim3(nblocks), dim3(256), 0, stream>>>(
                x_in, pos_in, pos4, pos_out4, pos_out, in_index, out_index, W1, W2, out, E, nwin, totwaves);
    }
    {
        const int ntiles = (n_out + 15) / 16;        // 16 nodes per tile
        const int nblocks = (ntiles + 7) / 8;        // ~2 tiles per wave
        const int totwaves = nblocks * 4;
        k_out<<<dim3(nblocks), dim3(256), 0, stream>>>(
            out, W3, b3, start, n_out, ntiles, totwaves);
    }
}